// Round 7
// baseline (220.513 us; speedup 1.0000x reference)
//
#include <hip/hip_runtime.h>
#include <cstddef>
#include <cstdint>

#define DIM  768
#define NH   12
#define HD   64
#define SEQ  2048
#define NB   2
#define NQKV 2304
#define G    (NB * NH * SEQ)   // 49152 total (b,h,s) rows

typedef _Float16 f16x8 __attribute__((ext_vector_type(8)));
typedef _Float16 f16x4 __attribute__((ext_vector_type(4)));
typedef float    f32x4 __attribute__((ext_vector_type(4)));
typedef float    f32x16 __attribute__((ext_vector_type(16)));

#if __has_builtin(__builtin_amdgcn_exp2f)
#define EXP2(x) __builtin_amdgcn_exp2f(x)
#else
#define EXP2(x) exp2f(x)
#endif

// q pre-scale: (1/sqrt(64)) * log2(e) -> softmax = exp2(s), no max-shift
// (constant shift cancels in normalization; |s2|<~9 so p<2^9 fits fp16)
#define QSCALE 0.1803368801111244f

// async global->LDS, 16B/lane; lds dest = wave-uniform base + lane*16B
__device__ __forceinline__ void gld16(const _Float16* g, _Float16* l) {
  __builtin_amdgcn_global_load_lds(
      (const __attribute__((address_space(1))) void*)g,
      (__attribute__((address_space(3))) void*)l, 16, 0, 0);
}

// ---------------------------------------------------------------------------
// transpose + convert: W[K][N] fp32 -> WT[N][K] fp16   (32x32 tiles)
// ---------------------------------------------------------------------------
__global__ __launch_bounds__(256) void transpose_cvt_kernel(
    const float* __restrict__ W, _Float16* __restrict__ WT, int K, int N) {
  __shared__ _Float16 tl[32][36];
  const int t = threadIdx.x;
  const int k0 = blockIdx.y * 32, n0 = blockIdx.x * 32;
  {
    const int r = t >> 3, c4 = (t & 7) * 4;
    float4 f = *(const float4*)(W + (size_t)(k0 + r) * N + n0 + c4);
    tl[r][c4 + 0] = (_Float16)f.x; tl[r][c4 + 1] = (_Float16)f.y;
    tl[r][c4 + 2] = (_Float16)f.z; tl[r][c4 + 3] = (_Float16)f.w;
  }
  __syncthreads();
  const int n = t >> 3, kc = (t & 7) * 4;
  f16x4 v;
  v[0] = tl[kc + 0][n]; v[1] = tl[kc + 1][n];
  v[2] = tl[kc + 2][n]; v[3] = tl[kc + 3][n];
  *(f16x4*)(WT + (size_t)(n0 + n) * K + k0 + kc) = v;
}

// ---------------------------------------------------------------------------
// fp16-MFMA GEMM v4: D[M,N] = A[M,K] @ BT[N,K]^T + bias
// 128x128 tile, BK=64 (half the barrier drains of BK=32), 256 thr,
// 2x2 waves of 64x64, mfma 16x16x32_f16. LDS [row][8 chunk8 slots] with
// XOR swizzle slot = c ^ (r&7) -> all ds traffic 2-way max (free).
// QKV=1: A is fp32 x, converted in register staging (no separate cvt pass);
//        scatter epilogue q (xQSCALE,[B,H,S,D]), k ([B,H,S,D]), v ([B,H,D,S]).
// QKV=0: A fp16 via gld16; dense fp32 store + bias.
// ---------------------------------------------------------------------------
template <int QKV>
__global__ __launch_bounds__(256) void gemm_f16_kernel(
    const void* __restrict__ Ap, const _Float16* __restrict__ BT,
    const float* __restrict__ bias, void* __restrict__ p0,
    void* __restrict__ p1, void* __restrict__ p2, int M, int N, int K) {
  __shared__ _Float16 As[128 * 64];
  __shared__ _Float16 Bs[128 * 64];
  const int tid = threadIdx.x;
  const int lane = tid & 63, wv = tid >> 6;
  const int wm = wv >> 1, wn = wv & 1;
  const int quad = lane >> 4, lcol = lane & 15;
  const int bm = blockIdx.y * 128, bn = blockIdx.x * 128;

  f32x4 acc[4][4];
#pragma unroll
  for (int i = 0; i < 4; i++)
#pragma unroll
    for (int j = 0; j < 4; j++) acc[i][j] = (f32x4)(0.f);

  // ---- staging geometry ----
  // gld16 call i: wave wv stages rows 32i + 8wv + (lane>>3), chunk8 = lane&7,
  // source k-offset swizzled by (c ^ (r&7)); LDS dest linear (= base+lane*16B).
  const _Float16* bsrc[4];
  _Float16* bdst[4];
  const _Float16* asrcH[4];   // QKV=0
  _Float16* adstH[4];
#pragma unroll
  for (int i = 0; i < 4; i++) {
    const int r = 32 * i + 8 * wv + (lane >> 3);
    const int c = lane & 7;
    const int koff = ((c ^ (r & 7)) * 8);
    bsrc[i] = BT + (size_t)(bn + r) * K + koff;
    bdst[i] = Bs + (32 * i + 8 * wv) * 64;
    if (!QKV) {
      asrcH[i] = (const _Float16*)Ap + (size_t)(bm + r) * K + koff;
      adstH[i] = As + (32 * i + 8 * wv) * 64;
    }
  }
  // QKV=1: fp32 A register staging: thread -> row tid>>1, chunks (tid&1)*4+w
  const int rA = tid >> 1;
  const float* asrcF[4];
  _Float16* adstF[4];
#pragma unroll
  for (int w = 0; w < 4; w++) {
    const int c = (tid & 1) * 4 + w;
    asrcF[w] = (const float*)Ap + (size_t)(bm + rA) * K + c * 8;
    adstF[w] = As + rA * 64 + ((c ^ (rA & 7)) * 8);
  }

  for (int k0 = 0; k0 < K; k0 += 64) {
    float4 av0[4], av1[4];
    if (QKV) {
#pragma unroll
      for (int w = 0; w < 4; w++) {
        av0[w] = *(const float4*)(asrcF[w] + k0);
        av1[w] = *(const float4*)(asrcF[w] + k0 + 4);
      }
    }
    __syncthreads();   // prev iteration's frag reads done
#pragma unroll
    for (int i = 0; i < 4; i++) gld16(bsrc[i] + k0, bdst[i]);
    if (!QKV) {
#pragma unroll
      for (int i = 0; i < 4; i++) gld16(asrcH[i] + k0, adstH[i]);
    } else {
#pragma unroll
      for (int w = 0; w < 4; w++) {
        f16x8 h;
        h[0] = (_Float16)av0[w].x; h[1] = (_Float16)av0[w].y;
        h[2] = (_Float16)av0[w].z; h[3] = (_Float16)av0[w].w;
        h[4] = (_Float16)av1[w].x; h[5] = (_Float16)av1[w].y;
        h[6] = (_Float16)av1[w].z; h[7] = (_Float16)av1[w].w;
        *(f16x8*)adstF[w] = h;
      }
    }
    __syncthreads();   // staging (vm + lgkm) drained

#pragma unroll
    for (int kk = 0; kk < 2; kk++) {
      f16x8 af[4], bf[4];
#pragma unroll
      for (int mi = 0; mi < 4; mi++) {
        const int R = wm * 64 + mi * 16 + lcol;
        const int q8 = kk * 4 + quad;
        af[mi] = *(const f16x8*)&As[R * 64 + ((q8 ^ (R & 7)) * 8)];
      }
#pragma unroll
      for (int ni = 0; ni < 4; ni++) {
        const int R = wn * 64 + ni * 16 + lcol;
        const int q8 = kk * 4 + quad;
        bf[ni] = *(const f16x8*)&Bs[R * 64 + ((q8 ^ (R & 7)) * 8)];
      }
#pragma unroll
      for (int mi = 0; mi < 4; mi++)
#pragma unroll
        for (int ni = 0; ni < 4; ni++)
          acc[mi][ni] = __builtin_amdgcn_mfma_f32_16x16x32_f16(af[mi], bf[ni], acc[mi][ni], 0, 0, 0);
    }
  }

  // epilogue: C/D layout col=lane&15, row=quad*4+reg
#pragma unroll
  for (int mi = 0; mi < 4; mi++) {
#pragma unroll
    for (int r = 0; r < 4; r++) {
      const int row = bm + wm * 64 + mi * 16 + quad * 4 + r;
      const int b_ = row >> 11, s_ = row & 2047;
#pragma unroll
      for (int ni = 0; ni < 4; ni++) {
        const int c = bn + wn * 64 + ni * 16 + lcol;
        const float val = acc[mi][ni][r] + bias[c];
        if (!QKV) {
          ((float*)p0)[(size_t)row * N + c] = val;
        } else {
          const int d = c & 63;
          const int which = c / 768;
          const int h = (c - which * 768) >> 6;
          if (which == 0)
            ((_Float16*)p0)[(((size_t)b_ * NH + h) * SEQ + s_) * HD + d] =
                (_Float16)(val * QSCALE);
          else if (which == 1)
            ((_Float16*)p1)[(((size_t)b_ * NH + h) * SEQ + s_) * HD + d] = (_Float16)val;
          else  // v stored transposed [B,H,D,S]
            ((_Float16*)p2)[(((size_t)b_ * NH + h) * HD + d) * SEQ + s_] = (_Float16)val;
        }
      }
    }
  }
}

// ---------------------------------------------------------------------------
// fp16-MFMA flash attention v7, split-K partial. Block = (bh, 128 q-rows, ks);
// 4 waves of 32 q-rows; 1024 keys/split (16 tiles of 64).
// K staged in LDS (stride 68, conflict-free). V B-frags read DIRECTLY from
// global vT[B,H,D,S] (K-contiguous 16B/lane), issued at loop top so ~200cyc
// of S-MFMA+softmax hides L1/L2 latency; sibling waves share via L1.
// p = exp2(s) (no max-shift, constant cancels in normalization).
// DS ops/tile-wave: 22 (was 32). Writes normalized O (fp16) + l (fp32).
// ---------------------------------------------------------------------------
#define PST 68
__global__ __launch_bounds__(256) void attn_part_kernel(
    const _Float16* __restrict__ Q, const _Float16* __restrict__ K,
    const _Float16* __restrict__ V, _Float16* __restrict__ Ohat,
    float* __restrict__ L) {
  __shared__ _Float16 Ks[64 * PST];    // [key][d]
  __shared__ _Float16 Ps[128 * PST];   // per-wave 32 rows: [qrow][key]
  const int tid = threadIdx.x, lane = tid & 63, wv = tid >> 6;
  const int lr = lane & 31, hw = lane >> 5;
  const int bh = blockIdx.x, qt = blockIdx.y, ks = blockIdx.z;
  const size_t base = (size_t)bh * SEQ * HD;

  // Q B-fragments (lane holds qrow=lr, k=d = f*16 + hw*8 + j)
  f16x8 qb[4];
  {
    const _Float16* qp = Q + base + (size_t)(qt * 128 + wv * 32 + lr) * HD + hw * 8;
#pragma unroll
    for (int f = 0; f < 4; f++) qb[f] = *(const f16x8*)(qp + f * 16);
  }

  f32x16 o0 = (f32x16)(0.f), o1 = (f32x16)(0.f);
  float l_part = 0.f;

  const int sr = tid >> 2;          // staging key row 0..63
  const int sc = (tid & 3) * 16;    // staging d part
  const _Float16* Kb = K + base + (size_t)ks * (SEQ / 2) * HD;
  const _Float16* Vr0 = V + base + (size_t)lr * SEQ + ks * (SEQ / 2) + hw * 8;
  const _Float16* Vr1 = V + base + (size_t)(32 + lr) * SEQ + ks * (SEQ / 2) + hw * 8;
  _Float16* pw = &Ps[(size_t)(wv * 32 + lr) * PST];
  const _Float16* pr = &Ps[(size_t)(wv * 32 + lr) * PST + hw * 8];

  for (int t = 0; t < (SEQ / 2) / 64; t++) {
    // K tile -> regs (for LDS staging)
    const _Float16* kp = Kb + (size_t)(t * 64 + sr) * HD + sc;
    f16x8 k0v = *(const f16x8*)kp, k1v = *(const f16x8*)(kp + 8);
    // V fragments direct from global, issued early (consumed ~200cyc later)
    f16x8 vbuf0[4], vbuf1[4];
#pragma unroll
    for (int f = 0; f < 4; f++) {
      vbuf0[f] = *(const f16x8*)(Vr0 + t * 64 + f * 16);
      vbuf1[f] = *(const f16x8*)(Vr1 + t * 64 + f * 16);
    }

    __syncthreads();   // prev tile's K-frag reads done
    *(f16x8*)&Ks[sr * PST + sc] = k0v;
    *(f16x8*)&Ks[sr * PST + sc + 8] = k1v;
    __syncthreads();

    // S^T = K . Q^T  (rows = 64 keys in 2 groups, cols = this wave's 32 q-rows)
    f32x16 s0 = (f32x16)(0.f), s1 = (f32x16)(0.f);
#pragma unroll
    for (int f = 0; f < 4; f++) {
      f16x8 ka0 = *(const f16x8*)&Ks[(lr) * PST + f * 16 + hw * 8];
      f16x8 ka1 = *(const f16x8*)&Ks[(32 + lr) * PST + f * 16 + hw * 8];
      s0 = __builtin_amdgcn_mfma_f32_32x32x16_f16(ka0, qb[f], s0, 0, 0, 0);
      s1 = __builtin_amdgcn_mfma_f32_32x32x16_f16(ka1, qb[f], s1, 0, 0, 0);
    }

    // p = exp2(s); per-lane l; packed b64 stores to Ps[qrow][key]
#pragma unroll
    for (int rg = 0; rg < 4; rg++) {
      f16x4 pk0, pk1;
#pragma unroll
      for (int i = 0; i < 4; i++) {
        const float p0 = EXP2(s0[rg * 4 + i]);
        const float p1 = EXP2(s1[rg * 4 + i]);
        l_part += p0 + p1;
        pk0[i] = (_Float16)p0;
        pk1[i] = (_Float16)p1;
      }
      *(f16x4*)&pw[0  + 8 * rg + 4 * hw] = pk0;
      *(f16x4*)&pw[32 + 8 * rg + 4 * hw] = pk1;
    }

    // O += P . V : A-frags from private P (LDS), B-frags = vbuf (registers)
#pragma unroll
    for (int f = 0; f < 4; f++) {
      f16x8 pa = *(const f16x8*)(pr + f * 16);
      o0 = __builtin_amdgcn_mfma_f32_32x32x16_f16(pa, vbuf0[f], o0, 0, 0, 0);
      o1 = __builtin_amdgcn_mfma_f32_32x32x16_f16(pa, vbuf1[f], o1, 0, 0, 0);
    }
  }

  // merge l across half-waves (keys split by hw), broadcast via LDS
  const float l_full = l_part + __shfl_xor(l_part, 32);
  __syncthreads();
  float* lsh = (float*)&Ps[(size_t)(wv * 32) * PST];
  if (hw == 0) lsh[lr] = l_full;
  __syncthreads();

  // write per-split normalized O (fp16) + l (fp32)
  const size_t rbase = (size_t)ks * G + (size_t)bh * SEQ + qt * 128 + wv * 32;
  if (hw == 0) L[rbase + lr] = l_full;
  float linv[16];
#pragma unroll
  for (int r = 0; r < 16; r++)
    linv[r] = 1.0f / lsh[(r & 3) + 8 * (r >> 2) + 4 * hw];
#pragma unroll
  for (int r = 0; r < 16; r++) {
    const int rr = (r & 3) + 8 * (r >> 2) + 4 * hw;
    _Float16* cp = Ohat + (rbase + rr) * HD;
    cp[lr]      = (_Float16)(o0[r] * linv[r]);
    cp[32 + lr] = (_Float16)(o1[r] * linv[r]);
  }
}

// ---------------------------------------------------------------------------
// merge the two key-splits: ctx = (l0*O0 + l1*O1)/(l0+l1), [B,S,INNER] fp16
// ---------------------------------------------------------------------------
__global__ __launch_bounds__(256) void attn_merge_kernel(
    const _Float16* __restrict__ Ohat, const float* __restrict__ L,
    _Float16* __restrict__ ctx) {
  const size_t gid = (size_t)blockIdx.x * 256 + threadIdx.x;
  const int row = (int)(gid >> 3);          // 0..G-1 = (bh, s)
  const int dp = ((int)gid & 7) * 8;
  const float l0 = L[row], l1 = L[G + row];
  const float w0 = l0 / (l0 + l1), w1 = 1.0f - w0;
  f16x8 a = *(const f16x8*)(Ohat + (size_t)row * HD + dp);
  f16x8 b = *(const f16x8*)(Ohat + ((size_t)G + row) * HD + dp);
  const int bh = row >> 11, s = row & 2047;
  const int b_ = bh / NH, h_ = bh % NH;
  f16x8 o;
#pragma unroll
  for (int j = 0; j < 8; j++)
    o[j] = (_Float16)(w0 * (float)a[j] + w1 * (float)b[j]);
  *(f16x8*)(ctx + ((size_t)b_ * SEQ + s) * DIM + h_ * HD + dp) = o;
}

// ---------------------------------------------------------------------------
extern "C" void kernel_launch(void* const* d_in, const int* in_sizes, int n_in,
                              void* d_out, int out_size, void* d_ws,
                              size_t ws_size, hipStream_t stream) {
  const float* x = (const float*)d_in[0];
  const float* w_qkv = (const float*)d_in[1];
  const float* b_qkv = (const float*)d_in[2];
  const float* w_out = (const float*)d_in[3];
  const float* b_out = (const float*)d_in[4];
  float* out = (float*)d_out;

  _Float16* wsh = (_Float16*)d_ws;
  size_t off = 0;
  const size_t hsz = (size_t)NB * NH * SEQ * HD;  // 3,145,728
  _Float16* wqkvT = wsh + off; off += (size_t)NQKV * DIM;
  _Float16* woutT = wsh + off; off += (size_t)DIM * DIM;
  _Float16* qh   = wsh + off; off += hsz;   // [B,H,S,D], pre-scaled QSCALE
  _Float16* kh   = wsh + off; off += hsz;   // [B,H,S,D]
  _Float16* vT   = wsh + off; off += hsz;   // [B,H,D,S]
  _Float16* ctxh = wsh + off; off += hsz;   // [B,S,INNER]
  _Float16* Ohat = wsh + off; off += 2 * hsz;  // 2 splits x [G,64]
  float*    Lbuf = (float*)(wsh + off);        // 2 x G fp32

  transpose_cvt_kernel<<<dim3(NQKV / 32, DIM / 32), 256, 0, stream>>>(w_qkv, wqkvT, DIM, NQKV);
  transpose_cvt_kernel<<<dim3(DIM / 32, DIM / 32), 256, 0, stream>>>(w_out, woutT, DIM, DIM);
  // QKV projection: A = x fp32, cvt fused into staging; scatter q/k/vT
  gemm_f16_kernel<1><<<dim3(NQKV / 128, (NB * SEQ) / 128), 256, 0, stream>>>(
      x, wqkvT, b_qkv, qh, kh, vT, NB * SEQ, NQKV, DIM);
  attn_part_kernel<<<dim3(NB * NH, SEQ / 128, 2), 256, 0, stream>>>(
      qh, kh, vT, Ohat, Lbuf);
  attn_merge_kernel<<<(G * HD) / (256 * 8), 256, 0, stream>>>(Ohat, Lbuf, ctxh);
  gemm_f16_kernel<0><<<dim3(DIM / 128, (NB * SEQ) / 128), 256, 0, stream>>>(
      ctxh, woutT, b_out, out, nullptr, nullptr, NB * SEQ, DIM, DIM);
}

// Round 8
// 178.684 us; speedup vs baseline: 1.2341x; 1.2341x over previous
//
#include <hip/hip_runtime.h>
#include <cstddef>
#include <cstdint>

#define DIM  768
#define NH   12
#define HD   64
#define SEQ  2048
#define NB   2
#define NQKV 2304
#define G    (NB * NH * SEQ)   // 49152 total (b,h,s) rows

typedef _Float16 f16x8 __attribute__((ext_vector_type(8)));
typedef _Float16 f16x4 __attribute__((ext_vector_type(4)));
typedef float    f32x4 __attribute__((ext_vector_type(4)));
typedef float    f32x16 __attribute__((ext_vector_type(16)));

#if __has_builtin(__builtin_amdgcn_exp2f)
#define EXP2(x) __builtin_amdgcn_exp2f(x)
#else
#define EXP2(x) exp2f(x)
#endif

// q pre-scale: (1/sqrt(64)) * log2(e) -> softmax uses raw v_exp_f32 (exp2)
#define QSCALE 0.1803368801111244f
#define C2     6.0f   // constant max in exp2 domain

// async global->LDS, 16B/lane; lds dest = wave-uniform base + lane*16B
__device__ __forceinline__ void gld16(const _Float16* g, _Float16* l) {
  __builtin_amdgcn_global_load_lds(
      (const __attribute__((address_space(1))) void*)g,
      (__attribute__((address_space(3))) void*)l, 16, 0, 0);
}

// ---------------------------------------------------------------------------
// transpose + convert: W[K][N] fp32 -> WT[N][K] fp16   (32x32 tiles)
// ---------------------------------------------------------------------------
__global__ __launch_bounds__(256) void transpose_cvt_kernel(
    const float* __restrict__ W, _Float16* __restrict__ WT, int K, int N) {
  __shared__ _Float16 tl[32][36];
  const int t = threadIdx.x;
  const int k0 = blockIdx.y * 32, n0 = blockIdx.x * 32;
  {
    const int r = t >> 3, c4 = (t & 7) * 4;
    float4 f = *(const float4*)(W + (size_t)(k0 + r) * N + n0 + c4);
    tl[r][c4 + 0] = (_Float16)f.x; tl[r][c4 + 1] = (_Float16)f.y;
    tl[r][c4 + 2] = (_Float16)f.z; tl[r][c4 + 3] = (_Float16)f.w;
  }
  __syncthreads();
  const int n = t >> 3, kc = (t & 7) * 4;
  f16x4 v;
  v[0] = tl[kc + 0][n]; v[1] = tl[kc + 1][n];
  v[2] = tl[kc + 2][n]; v[3] = tl[kc + 3][n];
  *(f16x4*)(WT + (size_t)(n0 + n) * K + k0 + kc) = v;
}

// ---------------------------------------------------------------------------
// fp16 transpose within (b,h): v[B,H,S,D] -> vT[B,H,D,S]  (64x64 tiles)
// ---------------------------------------------------------------------------
__global__ __launch_bounds__(256) void vtrans_kernel(
    const _Float16* __restrict__ v, _Float16* __restrict__ vT) {
  __shared__ _Float16 tl[64][68];
  const int t = threadIdx.x;
  const int bh = blockIdx.x, st = blockIdx.y;
  const size_t base = (size_t)bh * SEQ * HD;
  {
    const int s = t >> 2, dc = (t & 3) * 16;
    const _Float16* p = v + base + (size_t)(st * 64 + s) * HD + dc;
    f16x8 a = *(const f16x8*)p, b = *(const f16x8*)(p + 8);
    *(f16x8*)&tl[s][dc] = a;
    *(f16x8*)&tl[s][dc + 8] = b;
  }
  __syncthreads();
  const int d = t >> 2, sc = (t & 3) * 16;
  f16x8 o0, o1;
#pragma unroll
  for (int j = 0; j < 8; j++) { o0[j] = tl[sc + j][d]; o1[j] = tl[sc + 8 + j][d]; }
  _Float16* q = vT + base + (size_t)d * SEQ + st * 64 + sc;
  *(f16x8*)q = o0;
  *(f16x8*)(q + 8) = o1;
}

// ---------------------------------------------------------------------------
// QKV GEMM (R6 structure + fused x-cvt): [4096,768]fp32 @ [2304,768]^T + bias
// 128x128 tile, BK=32, 2x2 waves of 64x64, mfma 16x16x32_f16.
// A: fp32 x loaded 4-lanes/row (full 128B granules), cvt to fp16 in regs,
//    b128 LDS writes with XOR chunk swizzle (2-way banks max).
// B: gld16 async staging (R6 verbatim). Frag reads swizzled to match.
// Epilogue scatters q (xQSCALE), k, v -- all [B,H,S,D].
// ---------------------------------------------------------------------------
__global__ __launch_bounds__(256) void qkv_gemm_kernel(
    const float* __restrict__ X, const _Float16* __restrict__ BT,
    const float* __restrict__ bias, _Float16* __restrict__ q,
    _Float16* __restrict__ k, _Float16* __restrict__ v) {
  __shared__ _Float16 As[128 * 32];
  __shared__ _Float16 Bs[128 * 32];
  const int tid = threadIdx.x;
  const int lane = tid & 63, wv = tid >> 6;
  const int wm = wv >> 1, wn = wv & 1;
  const int quad = lane >> 4, lcol = lane & 15;
  const int bm = blockIdx.y * 128, bn = blockIdx.x * 128;
  const int K = DIM, N = NQKV;

  f32x4 acc[4][4];
#pragma unroll
  for (int i = 0; i < 4; i++)
#pragma unroll
    for (int j = 0; j < 4; j++) acc[i][j] = (f32x4)(0.f);

  // A staging: round i: row rA = 64i + (tid>>2), 8-float chunk cc = tid&3
  const float* asrc[2];
  _Float16* adst[2];
#pragma unroll
  for (int i = 0; i < 2; i++) {
    const int rA = 64 * i + (tid >> 2);
    const int cc = tid & 3;
    asrc[i] = X + (size_t)(bm + rA) * K + cc * 8;
    adst[i] = As + rA * 32 + ((cc ^ ((rA >> 1) & 3)) * 8);
  }
  // B staging (R6 verbatim)
  const int r0 = wv * 32 + (lane >> 2);
  const int kp = (((lane & 3) ^ ((r0 >> 1) & 3)) * 8);
  const _Float16* b0p = BT + (size_t)(bn + r0) * K + kp;
  const _Float16* b1p = BT + (size_t)(bn + r0 + 16) * K + kp;
  _Float16* lB0 = Bs + (wv * 2 + 0) * 512;
  _Float16* lB1 = Bs + (wv * 2 + 1) * 512;

  for (int k0 = 0; k0 < K; k0 += 32) {
    float4 a0[2], a1[2];
#pragma unroll
    for (int i = 0; i < 2; i++) {
      a0[i] = *(const float4*)(asrc[i] + k0);
      a1[i] = *(const float4*)(asrc[i] + k0 + 4);
    }
    __syncthreads();   // prev iteration's frag reads done
    gld16(b0p + k0, lB0);
    gld16(b1p + k0, lB1);
#pragma unroll
    for (int i = 0; i < 2; i++) {
      f16x8 h;
      h[0] = (_Float16)a0[i].x; h[1] = (_Float16)a0[i].y;
      h[2] = (_Float16)a0[i].z; h[3] = (_Float16)a0[i].w;
      h[4] = (_Float16)a1[i].x; h[5] = (_Float16)a1[i].y;
      h[6] = (_Float16)a1[i].z; h[7] = (_Float16)a1[i].w;
      *(f16x8*)adst[i] = h;
    }
    __syncthreads();   // staging (vm + lgkm) drained

    f16x8 af[4], bf[4];
#pragma unroll
    for (int mi = 0; mi < 4; mi++) {
      const int R = wm * 64 + mi * 16 + lcol;
      af[mi] = *(const f16x8*)&As[R * 32 + ((quad ^ ((R >> 1) & 3)) * 8)];
    }
#pragma unroll
    for (int ni = 0; ni < 4; ni++) {
      const int R = wn * 64 + ni * 16 + lcol;
      bf[ni] = *(const f16x8*)&Bs[R * 32 + ((quad ^ ((R >> 1) & 3)) * 8)];
    }
#pragma unroll
    for (int mi = 0; mi < 4; mi++)
#pragma unroll
      for (int ni = 0; ni < 4; ni++)
        acc[mi][ni] = __builtin_amdgcn_mfma_f32_16x16x32_f16(af[mi], bf[ni], acc[mi][ni], 0, 0, 0);
  }

  // epilogue: C/D layout col=lane&15, row=quad*4+reg; scatter to [B,H,S,D]
#pragma unroll
  for (int mi = 0; mi < 4; mi++) {
#pragma unroll
    for (int r = 0; r < 4; r++) {
      const int row = bm + wm * 64 + mi * 16 + quad * 4 + r;
      const int b_ = row >> 11, s_ = row & 2047;
#pragma unroll
      for (int ni = 0; ni < 4; ni++) {
        const int c = bn + wn * 64 + ni * 16 + lcol;
        const float val = acc[mi][ni][r] + bias[c];
        const int d = c & 63;
        const int which = c / 768;
        const int h = (c - which * 768) >> 6;
        const size_t idx = (((size_t)b_ * NH + h) * SEQ + s_) * HD + d;
        if (which == 0)      q[idx] = (_Float16)(val * QSCALE);
        else if (which == 1) k[idx] = (_Float16)val;
        else                 v[idx] = (_Float16)val;
      }
    }
  }
}

// ---------------------------------------------------------------------------
// fp16-MFMA flash attention, split-K partial (R6 verbatim, proven 47 us).
// Block = (bh, 128 q-rows, ks); 4 waves of 32 q-rows; 1024 keys per split.
// LDS-staged K/V (stride 68, conflict-free), S^T=K.Q^T, constant-max exp2
// softmax, per-lane l. Writes per-split NORMALIZED O (fp16) + l (fp32).
// ---------------------------------------------------------------------------
#define PST 68
__global__ __launch_bounds__(256) void attn_part_kernel(
    const _Float16* __restrict__ Q, const _Float16* __restrict__ K,
    const _Float16* __restrict__ V, _Float16* __restrict__ Ohat,
    float* __restrict__ L) {
  __shared__ _Float16 Ks[64 * PST];    // [key][d]
  __shared__ _Float16 Vs[64 * PST];    // [d][key]
  __shared__ _Float16 Ps[128 * PST];   // per-wave 32 rows: [qrow][key]
  const int tid = threadIdx.x, lane = tid & 63, wv = tid >> 6;
  const int lr = lane & 31, hw = lane >> 5;
  const int bh = blockIdx.x, qt = blockIdx.y, ks = blockIdx.z;
  const size_t base = (size_t)bh * SEQ * HD;

  f16x8 qb[4];
  {
    const _Float16* qp = Q + base + (size_t)(qt * 128 + wv * 32 + lr) * HD + hw * 8;
#pragma unroll
    for (int f = 0; f < 4; f++) qb[f] = *(const f16x8*)(qp + f * 16);
  }

  f32x16 o0 = (f32x16)(0.f), o1 = (f32x16)(0.f);
  float l_part = 0.f;

  const int sr = tid >> 2;
  const int sc = (tid & 3) * 16;
  const _Float16* Kb = K + base + (size_t)ks * (SEQ / 2) * HD;
  const _Float16* Vb = V + base + ks * (SEQ / 2);

  for (int t = 0; t < (SEQ / 2) / 64; t++) {
    const _Float16* kp = Kb + (size_t)(t * 64 + sr) * HD + sc;
    f16x8 k0v = *(const f16x8*)kp, k1v = *(const f16x8*)(kp + 8);
    const _Float16* vp = Vb + (size_t)sr * SEQ + t * 64 + sc;
    f16x8 v0v = *(const f16x8*)vp, v1v = *(const f16x8*)(vp + 8);

    __syncthreads();
    *(f16x8*)&Ks[sr * PST + sc] = k0v;
    *(f16x8*)&Ks[sr * PST + sc + 8] = k1v;
    *(f16x8*)&Vs[sr * PST + sc] = v0v;
    *(f16x8*)&Vs[sr * PST + sc + 8] = v1v;
    __syncthreads();

    f32x16 s0 = (f32x16)(0.f), s1 = (f32x16)(0.f);
#pragma unroll
    for (int f = 0; f < 4; f++) {
      f16x8 ka0 = *(const f16x8*)&Ks[(lr) * PST + f * 16 + hw * 8];
      f16x8 ka1 = *(const f16x8*)&Ks[(32 + lr) * PST + f * 16 + hw * 8];
      s0 = __builtin_amdgcn_mfma_f32_32x32x16_f16(ka0, qb[f], s0, 0, 0, 0);
      s1 = __builtin_amdgcn_mfma_f32_32x32x16_f16(ka1, qb[f], s1, 0, 0, 0);
    }

    _Float16* pw = &Ps[(size_t)(wv * 32 + lr) * PST];
#pragma unroll
    for (int rg = 0; rg < 4; rg++) {
      f16x4 pk0, pk1;
#pragma unroll
      for (int i = 0; i < 4; i++) {
        const float p0 = EXP2(s0[rg * 4 + i] - C2);
        const float p1 = EXP2(s1[rg * 4 + i] - C2);
        l_part += p0 + p1;
        pk0[i] = (_Float16)p0;
        pk1[i] = (_Float16)p1;
      }
      *(f16x4*)&pw[0  + 8 * rg + 4 * hw] = pk0;
      *(f16x4*)&pw[32 + 8 * rg + 4 * hw] = pk1;
    }

#pragma unroll
    for (int f = 0; f < 4; f++) {
      f16x8 pa  = *(const f16x8*)&Ps[(size_t)(wv * 32 + lr) * PST + f * 16 + hw * 8];
      f16x8 vb0 = *(const f16x8*)&Vs[(lr) * PST + f * 16 + hw * 8];
      f16x8 vb1 = *(const f16x8*)&Vs[(32 + lr) * PST + f * 16 + hw * 8];
      o0 = __builtin_amdgcn_mfma_f32_32x32x16_f16(pa, vb0, o0, 0, 0, 0);
      o1 = __builtin_amdgcn_mfma_f32_32x32x16_f16(pa, vb1, o1, 0, 0, 0);
    }
  }

  const float l_full = l_part + __shfl_xor(l_part, 32);
  __syncthreads();
  float* lsh = (float*)&Ps[(size_t)(wv * 32) * PST];
  if (hw == 0) lsh[lr] = l_full;
  __syncthreads();

  const size_t rbase = (size_t)ks * G + (size_t)bh * SEQ + qt * 128 + wv * 32;
  if (hw == 0) L[rbase + lr] = l_full;
  float linv[16];
#pragma unroll
  for (int r = 0; r < 16; r++)
    linv[r] = 1.0f / lsh[(r & 3) + 8 * (r >> 2) + 4 * hw];
#pragma unroll
  for (int r = 0; r < 16; r++) {
    const int rr = (r & 3) + 8 * (r >> 2) + 4 * hw;
    _Float16* cp = Ohat + (rbase + rr) * HD;
    cp[lr]      = (_Float16)(o0[r] * linv[r]);
    cp[32 + lr] = (_Float16)(o1[r] * linv[r]);
  }
}

// ---------------------------------------------------------------------------
// Output projection with FUSED split-K merge:
// out[4096,768] = merge(Ohat,L)[4096,768] @ woutT[768,768]^T + bias.
// 64x64 block tile, 4 waves of 32x32 (2x2 16x16x32 frags), BK=32, 24 iters.
// Grid 12x64 = 768 blocks (3/CU, 12 waves/CU). A-staging reads Ohat[2]+L,
// blends w0*O0+w1*O1 in registers (merge kernel + ctx round-trip removed).
// ---------------------------------------------------------------------------
__global__ __launch_bounds__(256) void out_gemm_kernel(
    const _Float16* __restrict__ Ohat, const float* __restrict__ L,
    const _Float16* __restrict__ WT, const float* __restrict__ bias,
    float* __restrict__ out) {
  __shared__ _Float16 As[64 * 36];
  __shared__ _Float16 Bs[64 * 36];
  const int tid = threadIdx.x, lane = tid & 63, wv = tid >> 6;
  const int wr = (wv >> 1) * 32, wc = (wv & 1) * 32;
  const int quad = lane >> 4, lcol = lane & 15;
  const int bm = blockIdx.y * 64, bn = blockIdx.x * 64;

  f32x4 acc[2][2];
#pragma unroll
  for (int i = 0; i < 2; i++)
#pragma unroll
    for (int j = 0; j < 2; j++) acc[i][j] = (f32x4)(0.f);

  const int ra = tid >> 2, ca = (tid & 3) * 8;   // A: row, 8-half chunk
  const int grow = bm + ra, b_ = grow >> 11, s_ = grow & 2047;

  for (int k0 = 0; k0 < DIM; k0 += 32) {
    const int h = k0 >> 6;
    const int lidx = (b_ * NH + h) * SEQ + s_;
    const size_t obase = (size_t)lidx * HD + (k0 & 32) + ca;
    f16x8 u0 = *(const f16x8*)(Ohat + obase);
    f16x8 u1 = *(const f16x8*)(Ohat + (size_t)G * HD + obase);
    const float l0 = L[lidx], l1 = L[G + lidx];
    const float w0 = l0 / (l0 + l1), w1 = 1.0f - w0;
    f16x8 bv = *(const f16x8*)(WT + (size_t)(bn + ra) * DIM + k0 + ca);

    __syncthreads();   // prev iteration's frag reads done
    f16x8 av;
#pragma unroll
    for (int j = 0; j < 8; j++)
      av[j] = (_Float16)(w0 * (float)u0[j] + w1 * (float)u1[j]);
    *(f16x8*)&As[ra * 36 + ca] = av;
    *(f16x8*)&Bs[ra * 36 + ca] = bv;
    __syncthreads();

    f16x8 af[2], bf[2];
#pragma unroll
    for (int mi = 0; mi < 2; mi++)
      af[mi] = *(const f16x8*)&As[(wr + mi * 16 + lcol) * 36 + quad * 8];
#pragma unroll
    for (int ni = 0; ni < 2; ni++)
      bf[ni] = *(const f16x8*)&Bs[(wc + ni * 16 + lcol) * 36 + quad * 8];
#pragma unroll
    for (int mi = 0; mi < 2; mi++)
#pragma unroll
      for (int ni = 0; ni < 2; ni++)
        acc[mi][ni] = __builtin_amdgcn_mfma_f32_16x16x32_f16(af[mi], bf[ni], acc[mi][ni], 0, 0, 0);
  }

#pragma unroll
  for (int mi = 0; mi < 2; mi++) {
#pragma unroll
    for (int r = 0; r < 4; r++) {
      const int row = bm + wr + mi * 16 + quad * 4 + r;
#pragma unroll
      for (int ni = 0; ni < 2; ni++) {
        const int col = bn + wc + ni * 16 + lcol;
        out[(size_t)row * DIM + col] = acc[mi][ni][r] + bias[col];
      }
    }
  }
}

// ---------------------------------------------------------------------------
extern "C" void kernel_launch(void* const* d_in, const int* in_sizes, int n_in,
                              void* d_out, int out_size, void* d_ws,
                              size_t ws_size, hipStream_t stream) {
  const float* x = (const float*)d_in[0];
  const float* w_qkv = (const float*)d_in[1];
  const float* b_qkv = (const float*)d_in[2];
  const float* w_out = (const float*)d_in[3];
  const float* b_out = (const float*)d_in[4];
  float* out = (float*)d_out;

  _Float16* wsh = (_Float16*)d_ws;
  size_t off = 0;
  const size_t hsz = (size_t)NB * NH * SEQ * HD;  // 3,145,728
  _Float16* wqkvT = wsh + off; off += (size_t)NQKV * DIM;
  _Float16* woutT = wsh + off; off += (size_t)DIM * DIM;
  _Float16* qh   = wsh + off; off += hsz;      // [B,H,S,D], pre-scaled QSCALE
  _Float16* kh   = wsh + off; off += hsz;      // [B,H,S,D]
  _Float16* vh   = wsh + off; off += hsz;      // [B,H,S,D]
  _Float16* vT   = wsh + off; off += hsz;      // [B,H,D,S]
  _Float16* Ohat = wsh + off; off += 2 * hsz;  // 2 splits x [G,64]
  float*    Lbuf = (float*)(wsh + off);        // 2 x G fp32

  transpose_cvt_kernel<<<dim3(NQKV / 32, DIM / 32), 256, 0, stream>>>(w_qkv, wqkvT, DIM, NQKV);
  transpose_cvt_kernel<<<dim3(DIM / 32, DIM / 32), 256, 0, stream>>>(w_out, woutT, DIM, DIM);
  qkv_gemm_kernel<<<dim3(NQKV / 128, (NB * SEQ) / 128), 256, 0, stream>>>(
      x, wqkvT, b_qkv, qh, kh, vh);
  vtrans_kernel<<<dim3(NB * NH, SEQ / 64), 256, 0, stream>>>(vh, vT);
  attn_part_kernel<<<dim3(NB * NH, SEQ / 128, 2), 256, 0, stream>>>(
      qh, kh, vT, Ohat, Lbuf);
  out_gemm_kernel<<<dim3(DIM / 64, (NB * SEQ) / 64), 256, 0, stream>>>(
      Ohat, Lbuf, woutT, b_out, out);
}